// Round 8
// baseline (237.312 us; speedup 1.0000x reference)
//
#include <hip/hip_runtime.h>
#include <cstdint>
#include <cstddef>

// ---------- types / helpers ----------
typedef __bf16 bf16x8 __attribute__((ext_vector_type(8)));
typedef float  f32x4  __attribute__((ext_vector_type(4)));
typedef unsigned short us;

#define DEV static __device__ __forceinline__

DEV us f2bf(float f) {
    unsigned int u = __builtin_bit_cast(unsigned int, f);
    u += 0x7FFFu + ((u >> 16) & 1u);   // RNE
    return (us)(u >> 16);
}
DEV unsigned int pack2bf(float a, float b) {   // [lo=a, hi=b], round-half-up (cheap)
    unsigned int ua = __builtin_bit_cast(unsigned int, a) + 0x8000u;
    unsigned int ub = __builtin_bit_cast(unsigned int, b) + 0x8000u;
    return (ua >> 16) | (ub & 0xFFFF0000u);    // -> v_perm_b32
}

DEV void gll16(const void* g, void* l) {   // 16B global->LDS direct (wave: +lane*16)
    __builtin_amdgcn_global_load_lds(
        (const __attribute__((address_space(1))) unsigned int*)g,
        (__attribute__((address_space(3))) unsigned int*)l, 16, 0, 0);
}

DEV bf16x8 ld_frag(const us* p) {
    return __builtin_bit_cast(bf16x8, *reinterpret_cast<const uint4*>(p));
}

// ---------- problem constants ----------
#define BB 4
#define TT 2048
#define CC 768
#define NH 12
#define DH 64
#define MM (BB*TT)          // 8192
#define QSCALE 0.1803368801111144f   // 0.125 * log2(e): softmax via exp2

// ---------- cast f32 -> bf16 ----------
__global__ __launch_bounds__(256)
void cast_k(const float* __restrict__ x, us* __restrict__ xb, int n4)
{
    int i = blockIdx.x * 256 + threadIdx.x;
    int stride = gridDim.x * 256;
    for (; i < n4; i += stride) {
        float4 f = reinterpret_cast<const float4*>(x)[i];
        ushort4 o;
        o.x = f2bf(f.x); o.y = f2bf(f.y); o.z = f2bf(f.z); o.w = f2bf(f.w);
        reinterpret_cast<ushort4*>(xb)[i] = o;
    }
}

// ---------- transpose f32 -> bf16: dst[Cc][R] = bf16(src[R][Cc]) ----------
__global__ __launch_bounds__(256)
void transpose_k(const float* __restrict__ src,
                 us* __restrict__ dst, int R, int Cc)
{
    __shared__ float tile[32][33];
    int c0 = blockIdx.x * 32, r0 = blockIdx.y * 32;
    int tx = threadIdx.x, ty = threadIdx.y;
#pragma unroll
    for (int i = 0; i < 4; ++i)
        tile[ty + i*8][tx] = src[(size_t)(r0 + ty + i*8) * Cc + c0 + tx];
    __syncthreads();
#pragma unroll
    for (int i = 0; i < 4; ++i)
        dst[(size_t)(c0 + ty + i*8) * R + r0 + tx] = f2bf(tile[tx][ty + i*8]);
}

// ---------- fraglet layouts (probe round 5: scattered frag loads = 81% of attn) ----------
// K packed so an attn K-frag wave-load is 1KB CONTIGUOUS:
//   offK(t,d) = (t>>4)*1024 + ((d>>3)&7)*128 + (t&15)*8 + (d&7)    [elems, per head]
//   frag (j,sub,hh): addr = (j*4+sub)*1024 + hh*512 + lane*8  (lane = quad*16+l16)
// V^T packed likewise:
//   offV(d,t) = (t>>6)*4096 + ((d>>4)&3)*1024 + ((t>>3)&7)*128 + (d&15)*8 + (t&7)
//   frag (j,dsub,kc): addr = j*4096 + dsub*1024 + kc*512 + lane*8
// Both bijective on [0, TT*DH).

// ---------- GEMM: C[M,N] = A[M,K](bf16) * Bt[N,K]^T + bias[N] ----------
// MODE 0: store f32 to Cout
// MODE 1: scatter qkv -> Qo(scaled)[B,H,T,D] / Ko fraglet / Vo fraglet  (bf16)
#define BM 128
#define BN 128
#define BK 32

template<int MODE>
__global__ __launch_bounds__(256)
void gemm_bt(const us* __restrict__ A,
             const us* __restrict__ Bt,
             const float* __restrict__ bias,
             float* __restrict__ Cout,
             us* __restrict__ Qo, us* __restrict__ Ko, us* __restrict__ Vo,
             int M, int N, int K)
{
    __shared__ __align__(16) us As[BM * BK];
    __shared__ __align__(16) us Bs[BN * BK];

    const int tid  = threadIdx.x;
    const int wave = tid >> 6, lane = tid & 63;
    const int quad = lane >> 4, l16 = lane & 15;
    const int waveM = (wave >> 1) * 64, waveN = (wave & 1) * 64;
    const int m0 = blockIdx.y * BM, n0 = blockIdx.x * BN;

    const f32x4 zero4 = {0.f, 0.f, 0.f, 0.f};
    f32x4 acc[4][4];
#pragma unroll
    for (int i = 0; i < 4; ++i)
#pragma unroll
        for (int j = 0; j < 4; ++j) acc[i][j] = zero4;

    const int lrow = lane >> 2, lch = (lane & 3) * 8;
    const int nk = K / BK;
    for (int kt = 0; kt < nk; ++kt) {
#pragma unroll
        for (int c = 0; c < 2; ++c) {
            int rb = (wave * 2 + c) * 16;
            int row = rb + lrow;
            gll16(A  + (size_t)(m0 + row) * K + kt * BK + lch, &As[rb * BK]);
            gll16(Bt + (size_t)(n0 + row) * K + kt * BK + lch, &Bs[rb * BK]);
        }
        __syncthreads();

        bf16x8 af[4], bfv[4];
#pragma unroll
        for (int mi = 0; mi < 4; ++mi)
            af[mi] = *reinterpret_cast<const bf16x8*>(&As[(waveM + mi * 16 + l16) * BK + quad * 8]);
#pragma unroll
        for (int ni = 0; ni < 4; ++ni)
            bfv[ni] = *reinterpret_cast<const bf16x8*>(&Bs[(waveN + ni * 16 + l16) * BK + quad * 8]);
#pragma unroll
        for (int mi = 0; mi < 4; ++mi)
#pragma unroll
            for (int ni = 0; ni < 4; ++ni)
                acc[mi][ni] = __builtin_amdgcn_mfma_f32_16x16x32_bf16(af[mi], bfv[ni], acc[mi][ni], 0, 0, 0);
        __syncthreads();
    }

    // epilogue: C/D layout col = l16, row = quad*4 + reg
#pragma unroll
    for (int mi = 0; mi < 4; ++mi) {
#pragma unroll
        for (int ni = 0; ni < 4; ++ni) {
            int n = n0 + waveN + ni * 16 + l16;
            float bv = bias[n];
            int mg = m0 + waveM + mi * 16 + quad * 4;   // first of 4 consecutive m
            if (MODE == 0) {
#pragma unroll
                for (int reg = 0; reg < 4; ++reg)
                    Cout[(size_t)(mg + reg) * N + n] = acc[mi][ni][reg] + bv;
            } else {
                int which = n / CC, c2 = n % CC;
                int h = c2 >> 6, d = c2 & 63;
                int b = mg >> 11, t0 = mg & 2047;
                size_t hb = (size_t)(b * NH + h) * TT * DH;
                if (which == 2) {
                    // V fraglet: 4 consecutive t stay contiguous -> one 8B store
                    size_t off = hb + (size_t)(t0 >> 6) * 4096 + (d >> 4) * 1024
                               + ((t0 >> 3) & 7) * 128 + (d & 15) * 8 + (t0 & 7);
                    ushort4 pk;
                    pk.x = f2bf(acc[mi][ni][0] + bv);
                    pk.y = f2bf(acc[mi][ni][1] + bv);
                    pk.z = f2bf(acc[mi][ni][2] + bv);
                    pk.w = f2bf(acc[mi][ni][3] + bv);
                    *reinterpret_cast<ushort4*>(Vo + off) = pk;
                } else if (which == 1) {
                    // K fraglet: per-reg scalar store, stride 8 elems
                    size_t off = hb + (size_t)(t0 >> 4) * 1024 + (d >> 3) * 128
                               + (t0 & 15) * 8 + (d & 7);
#pragma unroll
                    for (int reg = 0; reg < 4; ++reg)
                        Ko[off + reg * 8] = f2bf(acc[mi][ni][reg] + bv);
                } else {
#pragma unroll
                    for (int reg = 0; reg < 4; ++reg) {
                        size_t off = hb + (size_t)(t0 + reg) * DH + d;
                        Qo[off] = f2bf((acc[mi][ni][reg] + bv) * QSCALE);
                    }
                }
            }
        }
    }
}

// ---------- flash attention: split-key pairs + fraglet loads + fixed-shift softmax ----------
// Block = 128 threads (2 waves) owns pair {g_hi, g_lo=63-g_hi}, g_hi in 32..63:
//   wave0: g_hi tiles [0,16)  -> 16 tiles, never masked (keys<1024 <= rows)
//   wave1: g_lo [0,nkt_lo) + store; g_hi [16,nkt_hi) -> partial; 17 tiles total
// Fixed-shift softmax => partials merge by PLAIN ADDITION (l=l0+l1, O=O0+O1),
// no max/rescale. One __syncthreads; wave0 merges + stores g_hi.
// vs round-7: serial chain 33->17 tiles, block L2 tile-loads 66->33, waves 2x.
// (Round-3's split-key failed on the SCATTERED loads - fixed by fraglet, R5/R6.)
#define PST 72

DEV void attn_tiles(const us* __restrict__ Qh, const us* __restrict__ Kh,
                    const us* __restrict__ Vh, us* __restrict__ myP,
                    int g, int j0, int j1, int maskLast,
                    int quad, int l16, int lane,
                    float& lrA, float& lrB, f32x4* oA, f32x4* oB)
{
    const f32x4 zero4 = {0.f, 0.f, 0.f, 0.f};
    const int mA = g * 32 + l16;
    const int mB = mA + 16;

    bf16x8 qfA0 = ld_frag(Qh + (size_t)mA * DH + quad * 8);
    bf16x8 qfA1 = ld_frag(Qh + (size_t)mA * DH + 32 + quad * 8);
    bf16x8 qfB0 = ld_frag(Qh + (size_t)mB * DH + quad * 8);
    bf16x8 qfB1 = ld_frag(Qh + (size_t)mB * DH + 32 + quad * 8);

#pragma unroll 1
    for (int j = j0; j < j1; ++j) {
        const us* kb = Kh + (size_t)j * 4096;   // fraglet tile
        const us* vb = Vh + (size_t)j * 4096;

        // K frags: frag (sub,hh) = 1KB contiguous wave-load
        bf16x8 kf[4][2];
#pragma unroll
        for (int sub = 0; sub < 4; ++sub)
#pragma unroll
            for (int hh = 0; hh < 2; ++hh)
                kf[sub][hh] = ld_frag(kb + sub * 1024 + hh * 512 + lane * 8);

        // S^T = K Q^T for both 16-row groups (K frags shared)
        f32x4 sA[4], sB[4];
#pragma unroll
        for (int sub = 0; sub < 4; ++sub) {
            f32x4 t = __builtin_amdgcn_mfma_f32_16x16x32_bf16(kf[sub][0], qfA0, zero4, 0, 0, 0);
            sA[sub]  = __builtin_amdgcn_mfma_f32_16x16x32_bf16(kf[sub][1], qfA1, t, 0, 0, 0);
            f32x4 u = __builtin_amdgcn_mfma_f32_16x16x32_bf16(kf[sub][0], qfB0, zero4, 0, 0, 0);
            sB[sub]  = __builtin_amdgcn_mfma_f32_16x16x32_bf16(kf[sub][1], qfB1, u, 0, 0, 0);
        }

        // V frags: frag (dsub,kc) = 1KB contiguous wave-load
        bf16x8 vf[4][2];
#pragma unroll
        for (int dsub = 0; dsub < 4; ++dsub)
#pragma unroll
            for (int kc = 0; kc < 2; ++kc)
                vf[dsub][kc] = ld_frag(vb + dsub * 1024 + kc * 512 + lane * 8);

        // diagonal mask on last tile of a masked range (exp2(-inf)=0)
        if (maskLast && j == j1 - 1) {
#pragma unroll
            for (int sub = 0; sub < 4; ++sub)
#pragma unroll
                for (int reg = 0; reg < 4; ++reg) {
                    int key = j * 64 + sub * 16 + quad * 4 + reg;
                    if (key > mA) sA[sub][reg] = -INFINITY;
                    if (key > mB) sB[sub][reg] = -INFINITY;
                }
        }

        // fixed-shift softmax, group A: p = exp2(s), no max tracking
        {
            float rs = 0.f;
#pragma unroll
            for (int sub = 0; sub < 4; ++sub) {
                float p0 = exp2f(sA[sub][0]), p1 = exp2f(sA[sub][1]);
                float p2 = exp2f(sA[sub][2]), p3 = exp2f(sA[sub][3]);
                rs += (p0 + p1) + (p2 + p3);
                uint2 pk; pk.x = pack2bf(p0, p1); pk.y = pack2bf(p2, p3);
                *reinterpret_cast<uint2*>(&myP[l16 * PST + sub * 16 + quad * 4]) = pk;
            }
            rs += __shfl_xor(rs, 16);
            rs += __shfl_xor(rs, 32);
            lrA += rs;
        }
        // group B
        {
            float rs = 0.f;
#pragma unroll
            for (int sub = 0; sub < 4; ++sub) {
                float p0 = exp2f(sB[sub][0]), p1 = exp2f(sB[sub][1]);
                float p2 = exp2f(sB[sub][2]), p3 = exp2f(sB[sub][3]);
                rs += (p0 + p1) + (p2 + p3);
                uint2 pk; pk.x = pack2bf(p0, p1); pk.y = pack2bf(p2, p3);
                *reinterpret_cast<uint2*>(&myP[(16 + l16) * PST + sub * 16 + quad * 4]) = pk;
            }
            rs += __shfl_xor(rs, 16);
            rs += __shfl_xor(rs, 32);
            lrB += rs;
        }

        // O^T += V^T P (same-wave LDS dep -> compiler waits)
#pragma unroll
        for (int kc = 0; kc < 2; ++kc) {
            bf16x8 pfA = *reinterpret_cast<const bf16x8*>(&myP[l16 * PST + kc * 32 + quad * 8]);
            bf16x8 pfB = *reinterpret_cast<const bf16x8*>(&myP[(16 + l16) * PST + kc * 32 + quad * 8]);
#pragma unroll
            for (int d = 0; d < 4; ++d) {
                oA[d] = __builtin_amdgcn_mfma_f32_16x16x32_bf16(vf[d][kc], pfA, oA[d], 0, 0, 0);
                oB[d] = __builtin_amdgcn_mfma_f32_16x16x32_bf16(vf[d][kc], pfB, oB[d], 0, 0, 0);
            }
        }
    }
}

DEV void attn_store(us* __restrict__ Og, int b, int h, int mA, int quad,
                    float lrA, float lrB, const f32x4* oA, const f32x4* oB)
{
    const int mB = mA + 16;
    const float invA = 1.f / lrA, invB = 1.f / lrB;
    us* orowA = Og + ((size_t)(b * TT + mA)) * CC + h * DH;
    us* orowB = Og + ((size_t)(b * TT + mB)) * CC + h * DH;
#pragma unroll
    for (int d = 0; d < 4; ++d) {
        uint2 pa, pb;
        pa.x = pack2bf(oA[d][0] * invA, oA[d][1] * invA);
        pa.y = pack2bf(oA[d][2] * invA, oA[d][3] * invA);
        pb.x = pack2bf(oB[d][0] * invB, oB[d][1] * invB);
        pb.y = pack2bf(oB[d][2] * invB, oB[d][3] * invB);
        *reinterpret_cast<uint2*>(orowA + d * 16 + quad * 4) = pa;
        *reinterpret_cast<uint2*>(orowB + d * 16 + quad * 4) = pb;
    }
}

__global__ __launch_bounds__(128)
void attn_k(const us* __restrict__ Qg,
            const us* __restrict__ Kg,   // fraglet layout
            const us* __restrict__ Vt,   // fraglet layout
            us* __restrict__ Og)
{
    __shared__ __align__(16) us Ps[2][32 * PST];   // per-wave P[g16+m][key]
    __shared__ float Mrg[64 * 35];                 // wave1 -> wave0 partial (34f/lane)

    const int tid  = threadIdx.x;
    const int wave = tid >> 6, lane = tid & 63;
    const int quad = lane >> 4, l16 = lane & 15;

    // XCD-locality decode: xcd = id%8 (round-robin dispatch heuristic)
    const int id  = blockIdx.x;
    const int xcd = id & 7, s = id >> 3;           // s in 0..191
    const int bh  = xcd + 8 * (s >> 5);            // head 0..47, fixed XCD (6/XCD)
    const int pw  = s & 31;                        // 0..31

    const int g_hi = 32 + pw;                      // 32..63
    const int g_lo = 63 - g_hi;                    // 31..0
    const int nkt_hi = (g_hi >> 1) + 1;            // 17..32
    const int nkt_lo = (g_lo >> 1) + 1;            // 16..1 (= 33 - nkt_hi)

    const us* Qh = Qg + (size_t)bh * TT * DH;
    const us* Kh = Kg + (size_t)bh * TT * DH;
    const us* Vh = Vt + (size_t)bh * TT * DH;
    const int b = bh / NH, h = bh % NH;
    us* myP = Ps[wave];

    const f32x4 zero4 = {0.f, 0.f, 0.f, 0.f};
    f32x4 oA[4], oB[4];
#pragma unroll
    for (int i = 0; i < 4; ++i) { oA[i] = zero4; oB[i] = zero4; }
    float lrA = 0.f, lrB = 0.f;

    if (wave == 0) {
        // head of g_hi: 16 tiles, keys 0..1023 all < row 1024 -> never masked
        attn_tiles(Qh, Kh, Vh, myP, g_hi, 0, 16, 0, quad, l16, lane,
                   lrA, lrB, oA, oB);
    } else {
        // all of g_lo (independent output, store now)
        attn_tiles(Qh, Kh, Vh, myP, g_lo, 0, nkt_lo, 1, quad, l16, lane,
                   lrA, lrB, oA, oB);
        attn_store(Og, b, h, g_lo * 32 + l16, quad, lrA, lrB, oA, oB);

        // tail of g_hi (fresh partial; fixed-shift -> partial is a plain sum)
#pragma unroll
        for (int i = 0; i < 4; ++i) { oA[i] = zero4; oB[i] = zero4; }
        lrA = 0.f; lrB = 0.f;
        attn_tiles(Qh, Kh, Vh, myP, g_hi, 16, nkt_hi, 1, quad, l16, lane,
                   lrA, lrB, oA, oB);

        float* mp = &Mrg[lane * 35];
        mp[0] = lrA; mp[17] = lrB;
#pragma unroll
        for (int d = 0; d < 4; ++d)
#pragma unroll
            for (int r = 0; r < 4; ++r) {
                mp[1 + d * 4 + r]  = oA[d][r];
                mp[18 + d * 4 + r] = oB[d][r];
            }
    }

    __syncthreads();

    if (wave == 0) {
        // fixed-shift merge: plain addition of partials
        const float* mp = &Mrg[lane * 35];
        lrA += mp[0]; lrB += mp[17];
#pragma unroll
        for (int d = 0; d < 4; ++d)
#pragma unroll
            for (int r = 0; r < 4; ++r) {
                oA[d][r] += mp[1 + d * 4 + r];
                oB[d][r] += mp[18 + d * 4 + r];
            }
        attn_store(Og, b, h, g_hi * 32 + l16, quad, lrA, lrB, oA, oB);
    }
}

// ---------- launch ----------
extern "C" void kernel_launch(void* const* d_in, const int* in_sizes, int n_in,
                              void* d_out, int out_size, void* d_ws, size_t ws_size,
                              hipStream_t stream)
{
    const float* x      = (const float*)d_in[0];
    const float* w_attn = (const float*)d_in[1];
    const float* b_attn = (const float*)d_in[2];
    const float* w_proj = (const float*)d_in[3];
    const float* b_proj = (const float*)d_in[4];
    float* out = (float*)d_out;

    char* ws = (char*)d_ws;
    size_t off = 0;
    auto alloc = [&](size_t bytes) {
        void* p = ws + off;
        off += (bytes + 255) & ~(size_t)255;
        return p;
    };
    us* wtA = (us*)alloc((size_t)(3 * CC) * CC * 2);  // [2304][768] bf16
    us* wtP = (us*)alloc((size_t)CC * CC * 2);        // [768][768]  bf16
    us* xb  = (us*)alloc((size_t)MM * CC * 2);        // x as bf16
    us* Qb  = (us*)alloc((size_t)MM * CC * 2);        // [B,H,T,D]
    us* Kb  = (us*)alloc((size_t)MM * CC * 2);        // K fraglet
    us* Vtb = (us*)alloc((size_t)MM * CC * 2);        // V fraglet
    us* att = (us*)alloc((size_t)MM * CC * 2);        // [B,T,C]

    cast_k<<<1024, 256, 0, stream>>>(x, xb, MM * CC / 4);
    transpose_k<<<dim3((3 * CC) / 32, CC / 32), dim3(32, 8), 0, stream>>>(w_attn, wtA, CC, 3 * CC);
    transpose_k<<<dim3(CC / 32, CC / 32), dim3(32, 8), 0, stream>>>(w_proj, wtP, CC, CC);

    gemm_bt<1><<<dim3((3 * CC) / BN, MM / BM), 256, 0, stream>>>(
        xb, wtA, b_attn, nullptr, Qb, Kb, Vtb, MM, 3 * CC, CC);

    attn_k<<<dim3(32 * BB * NH), 128, 0, stream>>>(Qb, Kb, Vtb, att);

    gemm_bt<0><<<dim3(CC / BN, MM / BM), 256, 0, stream>>>(
        att, wtP, b_proj, out, nullptr, nullptr, nullptr, MM, CC, CC);

    (void)in_sizes; (void)n_in; (void)out_size; (void)ws_size;
}